// Round 8
// baseline (409.368 us; speedup 1.0000x reference)
//
#include <hip/hip_runtime.h>

#define BIG_Z_F 1000000.0f
#define N_MESH 8

// Native Clang vector types — required by __builtin_nontemporal_* (HIP's
// float4/int4 are structs and are rejected by the builtin).
typedef float f4 __attribute__((ext_vector_type(4)));
typedef int   i4 __attribute__((ext_vector_type(4)));
typedef unsigned char uc4 __attribute__((ext_vector_type(4)));

// R8: half-row-batched gather. R7 interleaved 12 gather loads with 4 stores
// per c4 iteration and split each 64B fmem line into 4 loads ~35 instrs
// apart. Now: per 16-channel half, all 48 gather loads (4 pixels x 3 rows x
// 4 chunks, line-coherent back-to-back) issue before any store -> deeper
// MLP + MSHR line merge. Everything else identical to R7.

// ---------------------------------------------------------------------------
// Kernel A: per-4-pixel cross-mesh reduction. win[j] = dup0 ? argmin : 0xFF.
// ---------------------------------------------------------------------------
__global__ __launch_bounds__(256) void raster_reduce(
    const f4* __restrict__ zbuf4,   // (N, HW/4)
    f4* __restrict__ maskO4,        // (N, HW/4)
    f4* __restrict__ zbO4,          // (N, HW/4)
    uc4* __restrict__ win4,         // (HW/4) ws
    const int* __restrict__ mdp,    // scalar mask_duplicate
    int HW4)
{
    const int q = blockIdx.x * blockDim.x + threadIdx.x;
    if (q >= HW4) return;
    const int md = *mdp;

    float z[N_MESH][4];
    #pragma unroll
    for (int n = 0; n < N_MESH; ++n) {
        const f4 v = __builtin_nontemporal_load(&zbuf4[n * HW4 + q]);
        z[n][0] = v.x; z[n][1] = v.y; z[n][2] = v.z; z[n][3] = v.w;
    }

    bool dup0[4]; int bidx[4];
    #pragma unroll
    for (int j = 0; j < 4; ++j) {
        int count = 0; float best = __builtin_inff(); int bi = 0;
        #pragma unroll
        for (int n = 0; n < N_MESH; ++n) {
            const float zv = z[n][j];
            count += (zv > -1.0f) ? 1 : 0;
            const float t = (zv < 0.0f) ? BIG_Z_F : zv;
            if (t < best) { best = t; bi = n; }   // strict < => first-win tie
        }
        dup0[j] = (count > 1);
        bidx[j] = bi;
    }

    #pragma unroll
    for (int n = 0; n < N_MESH; ++n) {
        f4 m, zb;
        #pragma unroll
        for (int j = 0; j < 4; ++j) {
            const bool dup = dup0[j] && ((md != 0) || (n != bidx[j]));
            m[j]  = (z[n][j] >= 0.0f) ? 1.0f : 0.0f;
            zb[j] = dup ? -1.0f : z[n][j];
        }
        __builtin_nontemporal_store(m,  &maskO4[n * HW4 + q]);
        __builtin_nontemporal_store(zb, &zbO4[n * HW4 + q]);
    }
    uc4 w;
    w.x = dup0[0] ? (unsigned char)bidx[0] : (unsigned char)0xFF;
    w.y = dup0[1] ? (unsigned char)bidx[1] : (unsigned char)0xFF;
    w.z = dup0[2] ? (unsigned char)bidx[2] : (unsigned char)0xFF;
    w.w = dup0[3] ? (unsigned char)bidx[3] : (unsigned char)0xFF;
    win4[q] = w;
}

// ---------------------------------------------------------------------------
// Kernel B: per-(mesh, 4 pixels). Fully branchless; half-row-batched gather;
// all outputs 16B NT stores.
// ---------------------------------------------------------------------------
__global__ __launch_bounds__(256) void raster_interp(
    const i4* __restrict__ p2f4,    // (N, HW/4)
    const f4* __restrict__ bary4,   // (N, HW/4, 3)
    const f4* __restrict__ dists4,  // (N, HW/4)
    const float* __restrict__ fmem, // (F,3,C)
    const uc4* __restrict__ win4,   // (HW/4)
    const int* __restrict__ mdp,
    f4* __restrict__ out_map4,      // (N,C,HW/4)
    f4* __restrict__ pO4,           // (N, HW/4)
    f4* __restrict__ dO4,           // (N, HW/4)
    f4* __restrict__ bcO4,          // (N, HW/4, 3)
    int* __restrict__ faceflag,     // (F+1) ws, pre-zeroed; slot F = dummy
    int HW4, int C, int F)
{
    const int q = blockIdx.x * blockDim.x + threadIdx.x;
    if (q >= HW4) return;
    const int n    = blockIdx.y;
    const int idx4 = n * HW4 + q;
    const int md   = *mdp;

    const uc4 wv = win4[q];
    const unsigned char w[4] = { wv.x, wv.y, wv.z, wv.w };

    const i4 praw = __builtin_nontemporal_load(&p2f4[idx4]);
    const f4 drw  = __builtin_nontemporal_load(&dists4[idx4]);
    const f4 bv0  = __builtin_nontemporal_load(&bary4[idx4 * 3 + 0]); // p0.xyz p1.x
    const f4 bv1  = __builtin_nontemporal_load(&bary4[idx4 * 3 + 1]); // p1.yz  p2.xy
    const f4 bv2  = __builtin_nontemporal_load(&bary4[idx4 * 3 + 2]); // p2.z   p3.xyz
    const int   pr[4] = { praw.x, praw.y, praw.z, praw.w };
    const float dr[4] = { drw.x, drw.y, drw.z, drw.w };
    const float br[4][3] = {
        { bv0.x, bv0.y, bv0.z },
        { bv0.w, bv1.x, bv1.y },
        { bv1.z, bv1.w, bv2.x },
        { bv2.y, bv2.z, bv2.w },
    };

    float bst[4][3];   // values stored to bcO (dup -> -1)
    float bc[4][3];    // compute coefficients (invalid -> 0 => out = 0)
    int   safe[4];
    f4 pOv, dOv;
    #pragma unroll
    for (int j = 0; j < 4; ++j) {
        const bool dup   = (w[j] != 0xFF) && ((md != 0) || (n != (int)w[j]));
        const int  p     = dup ? -1 : pr[j];
        const bool valid = (p >= 0);
        #pragma unroll
        for (int k = 0; k < 3; ++k) {
            bst[j][k] = dup ? -1.0f : br[j][k];
            bc[j][k]  = valid ? bst[j][k] : 0.0f;
        }
        safe[j] = valid ? p : 0;
        pOv[j]  = (float)p;
        dOv[j]  = dup ? -1.0f : dr[j];
        faceflag[valid ? p : F] = 1;   // branchless scatter; slot F = dummy
    }
    __builtin_nontemporal_store(pOv, &pO4[idx4]);
    __builtin_nontemporal_store(dOv, &dO4[idx4]);
    {
        f4 c0, c1, c2;
        c0.x = bst[0][0]; c0.y = bst[0][1]; c0.z = bst[0][2]; c0.w = bst[1][0];
        c1.x = bst[1][1]; c1.y = bst[1][2]; c1.z = bst[2][0]; c1.w = bst[2][1];
        c2.x = bst[2][2]; c2.y = bst[3][0]; c2.z = bst[3][1]; c2.w = bst[3][2];
        __builtin_nontemporal_store(c0, &bcO4[idx4 * 3 + 0]);
        __builtin_nontemporal_store(c1, &bcO4[idx4 * 3 + 1]);
        __builtin_nontemporal_store(c2, &bcO4[idx4 * 3 + 2]);
    }

    const float* ab[4];
    #pragma unroll
    for (int j = 0; j < 4; ++j)
        ab[j] = fmem + (size_t)safe[j] * 3 * C;

    // Half-row-batched gather: per 16-channel half, all 4 pixels' 3x64B face
    // row-halves load back-to-back (12 f4 each, line-coherent), THEN the 16
    // transposed stores. 48 independent loads in flight per half.
    #pragma unroll
    for (int h = 0; h < 32; h += 16) {
        f4 r[4][4];   // r[j][t] = channels h+4t..h+4t+3 of pixel j
        #pragma unroll
        for (int j = 0; j < 4; ++j) {
            const float* a = ab[j] + h;
            f4 A0[4], A1[4], A2[4];
            #pragma unroll
            for (int t = 0; t < 4; ++t) A0[t] = *(const f4*)(a + 4 * t);
            #pragma unroll
            for (int t = 0; t < 4; ++t) A1[t] = *(const f4*)(a + C + 4 * t);
            #pragma unroll
            for (int t = 0; t < 4; ++t) A2[t] = *(const f4*)(a + 2 * C + 4 * t);
            #pragma unroll
            for (int t = 0; t < 4; ++t)
                r[j][t] = bc[j][0] * A0[t] + bc[j][1] * A1[t] + bc[j][2] * A2[t];
        }
        #pragma unroll
        for (int t = 0; t < 4; ++t) {
            #pragma unroll
            for (int k = 0; k < 4; ++k) {    // transpose to pixel-major
                f4 o;
                o.x = r[0][t][k]; o.y = r[1][t][k]; o.z = r[2][t][k]; o.w = r[3][t][k];
                __builtin_nontemporal_store(
                    o, &out_map4[(size_t)(n * C + h + 4 * t + k) * HW4 + q]);
            }
        }
    }
}

// Scatter vertex visibility from face-visibility flags.
__global__ __launch_bounds__(256) void vert_vis(
    const int* __restrict__ faceflag,
    const int* __restrict__ pfaces,     // (F,3)
    float* __restrict__ vv,             // (V), pre-zeroed
    int F)
{
    const int f = blockIdx.x * blockDim.x + threadIdx.x;
    if (f >= F) return;
    if (faceflag[f]) {
        vv[pfaces[f * 3 + 0]] = 1.0f;
        vv[pfaces[f * 3 + 1]] = 1.0f;
        vv[pfaces[f * 3 + 2]] = 1.0f;
    }
}

extern "C" void kernel_launch(void* const* d_in, const int* in_sizes, int n_in,
                              void* d_out, int out_size, void* d_ws, size_t ws_size,
                              hipStream_t stream) {
    const float* zbuf   = (const float*)d_in[0];
    const int*   p2f    = (const int*)  d_in[1];
    const float* bary   = (const float*)d_in[2];
    const float* dists  = (const float*)d_in[3];
    const float* fmem   = (const float*)d_in[4];
    const int*   pfaces = (const int*)  d_in[5];
    // d_in[6] = num_verts (device scalar; V derived from out_size instead)
    const int*   mdp    = (const int*)  d_in[7];

    const long long P  = in_sizes[0];        // N*H*W*K = 2097152
    const int HW  = (int)(P / N_MESH);       // 262144 pixels
    const int HW4 = HW / 4;                  // 65536
    const int F3  = in_sizes[5];             // F*3
    const int F   = F3 / 3;                  // 20000
    const int C   = in_sizes[4] / F3;        // 32
    const int V   = (int)((long long)out_size - P * C - 7 * P);  // 10002

    float* out     = (float*)d_out;
    float* out_map = out;                    // P*C
    float* vv      = out_map + P * C;        // V
    float* maskO   = vv + V;                 // P
    float* zbO     = maskO + P;              // P
    float* pO      = zbO + P;                // P
    float* dO      = pO + P;                 // P
    float* bcO     = dO + P;                 // 3P

    int* faceflag = (int*)d_ws;                 // F+1 ints (slot F = dummy)
    uc4* win4     = (uc4*)(faceflag + F + 4);   // HW bytes

    (void)hipMemsetAsync(faceflag, 0, (size_t)(F + 1) * sizeof(int), stream);
    (void)hipMemsetAsync(vv, 0, (size_t)V * sizeof(float), stream);

    raster_reduce<<<dim3(HW4 / 256), dim3(256), 0, stream>>>(
        (const f4*)zbuf, (f4*)maskO, (f4*)zbO, win4, mdp, HW4);

    raster_interp<<<dim3(HW4 / 256, N_MESH), dim3(256), 0, stream>>>(
        (const i4*)p2f, (const f4*)bary, (const f4*)dists, fmem,
        (const uc4*)win4, mdp,
        (f4*)out_map, (f4*)pO, (f4*)dO, (f4*)bcO,
        faceflag, HW4, C, F);

    vert_vis<<<dim3((F + 255) / 256), dim3(256), 0, stream>>>(
        faceflag, pfaces, vv, F);
}

// Round 9
// 387.710 us; speedup vs baseline: 1.0559x; 1.0559x over previous
//
#include <hip/hip_runtime.h>

#define BIG_Z_F 1000000.0f
#define N_MESH 8

// Native Clang vector types — required by __builtin_nontemporal_* (HIP's
// float4/int4 are structs and are rejected by the builtin).
typedef float f4 __attribute__((ext_vector_type(4)));
typedef int   i4 __attribute__((ext_vector_type(4)));
typedef unsigned char uc4 __attribute__((ext_vector_type(4)));

// R9 = R7 (best known: branchless gather, 16B NT everything, c4-chunked
// interp loop with 16-f4 live set) + the faceflag/vv zeroing folded into
// kernel A (removes 2 memset dispatches from the graph).
// R8's half-row load batching REGRESSED (+15us): 48 live f4 temps -> VGPR
// pressure. Do not re-batch.

// ---------------------------------------------------------------------------
// Kernel A: per-4-pixel cross-mesh reduction + ws zero-init.
// win[j] = dup0 ? argmin : 0xFF.
// ---------------------------------------------------------------------------
__global__ __launch_bounds__(256) void raster_reduce(
    const f4* __restrict__ zbuf4,   // (N, HW/4)
    f4* __restrict__ maskO4,        // (N, HW/4)
    f4* __restrict__ zbO4,          // (N, HW/4)
    uc4* __restrict__ win4,         // (HW/4) ws
    int* __restrict__ faceflag,     // (F+1) ws — zeroed here, used by B
    float* __restrict__ vv,         // (V) out — zeroed here, used by vert_vis
    const int* __restrict__ mdp,    // scalar mask_duplicate
    int HW4, int F, int V)
{
    const int q = blockIdx.x * blockDim.x + threadIdx.x;
    if (q >= HW4) return;

    // Folded zero-init (A runs before B / vert_vis; stream-ordered).
    if (q <= F) faceflag[q] = 0;
    if (q < V)  vv[q] = 0.0f;

    const int md = *mdp;

    float z[N_MESH][4];
    #pragma unroll
    for (int n = 0; n < N_MESH; ++n) {
        const f4 v = __builtin_nontemporal_load(&zbuf4[n * HW4 + q]);
        z[n][0] = v.x; z[n][1] = v.y; z[n][2] = v.z; z[n][3] = v.w;
    }

    bool dup0[4]; int bidx[4];
    #pragma unroll
    for (int j = 0; j < 4; ++j) {
        int count = 0; float best = __builtin_inff(); int bi = 0;
        #pragma unroll
        for (int n = 0; n < N_MESH; ++n) {
            const float zv = z[n][j];
            count += (zv > -1.0f) ? 1 : 0;
            const float t = (zv < 0.0f) ? BIG_Z_F : zv;
            if (t < best) { best = t; bi = n; }   // strict < => first-win tie
        }
        dup0[j] = (count > 1);
        bidx[j] = bi;
    }

    #pragma unroll
    for (int n = 0; n < N_MESH; ++n) {
        f4 m, zb;
        #pragma unroll
        for (int j = 0; j < 4; ++j) {
            const bool dup = dup0[j] && ((md != 0) || (n != bidx[j]));
            m[j]  = (z[n][j] >= 0.0f) ? 1.0f : 0.0f;
            zb[j] = dup ? -1.0f : z[n][j];
        }
        __builtin_nontemporal_store(m,  &maskO4[n * HW4 + q]);
        __builtin_nontemporal_store(zb, &zbO4[n * HW4 + q]);
    }
    uc4 w;
    w.x = dup0[0] ? (unsigned char)bidx[0] : (unsigned char)0xFF;
    w.y = dup0[1] ? (unsigned char)bidx[1] : (unsigned char)0xFF;
    w.z = dup0[2] ? (unsigned char)bidx[2] : (unsigned char)0xFF;
    w.w = dup0[3] ? (unsigned char)bidx[3] : (unsigned char)0xFF;
    win4[q] = w;
}

// ---------------------------------------------------------------------------
// Kernel B: per-(mesh, 4 pixels). Fully branchless: no exec-mask regions in
// the gather/interp path. All outputs 16B NT stores. (R7 structure.)
// ---------------------------------------------------------------------------
__global__ __launch_bounds__(256) void raster_interp(
    const i4* __restrict__ p2f4,    // (N, HW/4)
    const f4* __restrict__ bary4,   // (N, HW/4, 3)
    const f4* __restrict__ dists4,  // (N, HW/4)
    const float* __restrict__ fmem, // (F,3,C)
    const uc4* __restrict__ win4,   // (HW/4)
    const int* __restrict__ mdp,
    f4* __restrict__ out_map4,      // (N,C,HW/4)
    f4* __restrict__ pO4,           // (N, HW/4)
    f4* __restrict__ dO4,           // (N, HW/4)
    f4* __restrict__ bcO4,          // (N, HW/4, 3)
    int* __restrict__ faceflag,     // (F+1) ws, pre-zeroed; slot F = dummy
    int HW4, int C, int F)
{
    const int q = blockIdx.x * blockDim.x + threadIdx.x;
    if (q >= HW4) return;
    const int n    = blockIdx.y;
    const int idx4 = n * HW4 + q;
    const int md   = *mdp;

    const uc4 wv = win4[q];
    const unsigned char w[4] = { wv.x, wv.y, wv.z, wv.w };

    const i4 praw = __builtin_nontemporal_load(&p2f4[idx4]);
    const f4 drw  = __builtin_nontemporal_load(&dists4[idx4]);
    const f4 bv0  = __builtin_nontemporal_load(&bary4[idx4 * 3 + 0]); // p0.xyz p1.x
    const f4 bv1  = __builtin_nontemporal_load(&bary4[idx4 * 3 + 1]); // p1.yz  p2.xy
    const f4 bv2  = __builtin_nontemporal_load(&bary4[idx4 * 3 + 2]); // p2.z   p3.xyz
    const int   pr[4] = { praw.x, praw.y, praw.z, praw.w };
    const float dr[4] = { drw.x, drw.y, drw.z, drw.w };
    const float br[4][3] = {
        { bv0.x, bv0.y, bv0.z },
        { bv0.w, bv1.x, bv1.y },
        { bv1.z, bv1.w, bv2.x },
        { bv2.y, bv2.z, bv2.w },
    };

    float bst[4][3];   // values stored to bcO (dup -> -1)
    float bc[4][3];    // compute coefficients (invalid -> 0 => out = 0)
    int   safe[4];
    f4 pOv, dOv;
    #pragma unroll
    for (int j = 0; j < 4; ++j) {
        const bool dup   = (w[j] != 0xFF) && ((md != 0) || (n != (int)w[j]));
        const int  p     = dup ? -1 : pr[j];
        const bool valid = (p >= 0);
        #pragma unroll
        for (int k = 0; k < 3; ++k) {
            bst[j][k] = dup ? -1.0f : br[j][k];
            bc[j][k]  = valid ? bst[j][k] : 0.0f;
        }
        safe[j] = valid ? p : 0;
        pOv[j]  = (float)p;
        dOv[j]  = dup ? -1.0f : dr[j];
        faceflag[valid ? p : F] = 1;   // branchless scatter; slot F = dummy
    }
    __builtin_nontemporal_store(pOv, &pO4[idx4]);
    __builtin_nontemporal_store(dOv, &dO4[idx4]);
    {
        f4 c0, c1, c2;
        c0.x = bst[0][0]; c0.y = bst[0][1]; c0.z = bst[0][2]; c0.w = bst[1][0];
        c1.x = bst[1][1]; c1.y = bst[1][2]; c1.z = bst[2][0]; c1.w = bst[2][1];
        c2.x = bst[2][2]; c2.y = bst[3][0]; c2.z = bst[3][1]; c2.w = bst[3][2];
        __builtin_nontemporal_store(c0, &bcO4[idx4 * 3 + 0]);
        __builtin_nontemporal_store(c1, &bcO4[idx4 * 3 + 1]);
        __builtin_nontemporal_store(c2, &bcO4[idx4 * 3 + 2]);
    }

    const float* ab[4];
    #pragma unroll
    for (int j = 0; j < 4; ++j)
        ab[j] = fmem + (size_t)safe[j] * 3 * C;

    #pragma unroll
    for (int c4 = 0; c4 < 32; c4 += 4) {     // C == 32
        f4 r[4];   // r[j] = channels c4..c4+3 of pixel j (channel-major)
        #pragma unroll
        for (int j = 0; j < 4; ++j) {
            const float* a = ab[j];
            const f4 a0 = *(const f4*)(a + c4);
            const f4 a1 = *(const f4*)(a + C + c4);
            const f4 a2 = *(const f4*)(a + 2 * C + c4);
            r[j] = bc[j][0] * a0 + bc[j][1] * a1 + bc[j][2] * a2;
        }
        #pragma unroll
        for (int k = 0; k < 4; ++k) {        // transpose to pixel-major
            f4 o;
            o.x = r[0][k]; o.y = r[1][k]; o.z = r[2][k]; o.w = r[3][k];
            __builtin_nontemporal_store(o, &out_map4[(size_t)(n * C + c4 + k) * HW4 + q]);
        }
    }
}

// Scatter vertex visibility from face-visibility flags.
__global__ __launch_bounds__(256) void vert_vis(
    const int* __restrict__ faceflag,
    const int* __restrict__ pfaces,     // (F,3)
    float* __restrict__ vv,             // (V), pre-zeroed by kernel A
    int F)
{
    const int f = blockIdx.x * blockDim.x + threadIdx.x;
    if (f >= F) return;
    if (faceflag[f]) {
        vv[pfaces[f * 3 + 0]] = 1.0f;
        vv[pfaces[f * 3 + 1]] = 1.0f;
        vv[pfaces[f * 3 + 2]] = 1.0f;
    }
}

extern "C" void kernel_launch(void* const* d_in, const int* in_sizes, int n_in,
                              void* d_out, int out_size, void* d_ws, size_t ws_size,
                              hipStream_t stream) {
    const float* zbuf   = (const float*)d_in[0];
    const int*   p2f    = (const int*)  d_in[1];
    const float* bary   = (const float*)d_in[2];
    const float* dists  = (const float*)d_in[3];
    const float* fmem   = (const float*)d_in[4];
    const int*   pfaces = (const int*)  d_in[5];
    // d_in[6] = num_verts (device scalar; V derived from out_size instead)
    const int*   mdp    = (const int*)  d_in[7];

    const long long P  = in_sizes[0];        // N*H*W*K = 2097152
    const int HW  = (int)(P / N_MESH);       // 262144 pixels
    const int HW4 = HW / 4;                  // 65536
    const int F3  = in_sizes[5];             // F*3
    const int F   = F3 / 3;                  // 20000
    const int C   = in_sizes[4] / F3;        // 32
    const int V   = (int)((long long)out_size - P * C - 7 * P);  // 10002

    float* out     = (float*)d_out;
    float* out_map = out;                    // P*C
    float* vv      = out_map + P * C;        // V
    float* maskO   = vv + V;                 // P
    float* zbO     = maskO + P;              // P
    float* pO      = zbO + P;                // P
    float* dO      = pO + P;                 // P
    float* bcO     = dO + P;                 // 3P

    int* faceflag = (int*)d_ws;                 // F+1 ints (slot F = dummy)
    uc4* win4     = (uc4*)(faceflag + F + 4);   // HW bytes

    raster_reduce<<<dim3(HW4 / 256), dim3(256), 0, stream>>>(
        (const f4*)zbuf, (f4*)maskO, (f4*)zbO, win4, faceflag, vv, mdp,
        HW4, F, V);

    raster_interp<<<dim3(HW4 / 256, N_MESH), dim3(256), 0, stream>>>(
        (const i4*)p2f, (const f4*)bary, (const f4*)dists, fmem,
        (const uc4*)win4, mdp,
        (f4*)out_map, (f4*)pO, (f4*)dO, (f4*)bcO,
        faceflag, HW4, C, F);

    vert_vis<<<dim3((F + 255) / 256), dim3(256), 0, stream>>>(
        faceflag, pfaces, vv, F);
}